// Round 9
// baseline (701.424 us; speedup 1.0000x reference)
//
#include <hip/hip_runtime.h>
#include <hip/hip_bf16.h>

// Problem constants
#define BB 32    // batch
#define TT 128   // T_E == T_D
#define HH 256   // hidden
#define G4 4     // blocks per batch for LSTM
#define UPB 64   // units per LSTM block (256/4)
#define RPB 256  // gate rows per LSTM block (4 gates * 64 units)

#define AGENT __HIP_MEMORY_SCOPE_AGENT
#define AL(p) __hip_atomic_load((p), __ATOMIC_RELAXED, AGENT)

__device__ __forceinline__ float rcp_f(float x) { return __builtin_amdgcn_rcpf(x); }
__device__ __forceinline__ float sigmoid_f(float x) {
    return rcp_f(1.f + __expf(-x));  // v_rcp: ~1e-7 rel err, threshold is 7e-3
}
__device__ __forceinline__ float tanh_f(float x) {
    float e = __expf(2.f * x);
    return 1.f - 2.f * rcp_f(e + 1.f);
}

// ---------------------------------------------------------------------------
// Prep: transpose We, Wd (256x256), tiled+coalesced.
// ---------------------------------------------------------------------------
__global__ __launch_bounds__(256) void prep_transpose(
    const float* __restrict__ We, const float* __restrict__ Wd,
    float* __restrict__ WeT, float* __restrict__ WdT) {
    __shared__ float t[64][65];
    const int m = blockIdx.x >> 4;
    const int tile = blockIdx.x & 15;
    const float* S = m ? Wd : We;
    float* D = m ? WdT : WeT;
    const int r0 = (tile >> 2) * 64, c0 = (tile & 3) * 64;
    const int lr = threadIdx.x >> 4;
    const int lc = threadIdx.x & 15;
    for (int rr = lr; rr < 64; rr += 16)
        *(float4*)&t[rr][lc * 4] = *(const float4*)&S[(r0 + rr) * HH + c0 + lc * 4];
    __syncthreads();
    for (int rr = lr; rr < 64; rr += 16) {
        float4 v;
        v.x = t[lc * 4 + 0][rr];
        v.y = t[lc * 4 + 1][rr];
        v.z = t[lc * 4 + 2][rr];
        v.w = t[lc * 4 + 3][rr];
        *(float4*)&D[(c0 + rr) * HH + r0 + lc * 4] = v;
    }
}

// ---------------------------------------------------------------------------
// LSTM (tagged mailbox + ring poll; critical path = publish + detect only).
// grid = 128 (blk = g*32 + b); block = 512 = 8 waves; weights in registers,
// wave-uniform k-half -> phase-1 LDS reads are pure broadcasts (0 conflicts).
// R9 changes vs R8:
//  * ring-poll prefill issues 4 loads BACK-TO-BACK, first check immediately
//    (R8's s_sleep stagger burned ~576 cyc/step before any check);
//  * e_out/d_out global stores moved OFF wave 0: phase 2 writes h to a 2-slot
//    LDS history; idle wave 4 stores step t-1's h during step t's poll window
//    (store-ack overlaps the wait, not the producer's pre-barrier vmcnt(0)).
// ---------------------------------------------------------------------------
__global__ __launch_bounds__(512, 2) void lstm_kernel(
    const float* __restrict__ seq,     // [B][128]
    const int* __restrict__ seq_m,     // [B]
    const float* __restrict__ target,  // [B][128]
    const float* __restrict__ Wih_e,   // [1024]
    const float* __restrict__ Whh_e,   // [1024][256]
    const float* __restrict__ bih_e, const float* __restrict__ bhh_e,
    const float* __restrict__ Wih_d, const float* __restrict__ Whh_d,
    const float* __restrict__ bih_d, const float* __restrict__ bhh_d,
    float* __restrict__ e_out,  // [B][128][256]
    float* __restrict__ d_out,  // [B][128][256]
    unsigned long long* __restrict__ mbox,   // [2][B][256] tagged h packets
    unsigned long long* __restrict__ hsave)  // [B][256] tag-1 enc state @ last
{
    const int blk = blockIdx.x;
    const int b = blk & 31;   // batch
    const int g = blk >> 5;   // group slice 0..3
    const int tid = threadIdx.x;
    const int wave = tid >> 6;
    const int lane = tid & 63;
    const int half = wave & 1;                 // k-half (wave-uniform)
    const int row = (wave >> 1) * 64 + lane;   // 0..255 gate row in block
    const int gate = row >> 6;
    const int u_local = row & 63;
    const int row_global = gate * HH + g * UPB + u_local;
    const int last = seq_m[b] - 1;

    __shared__ float h_lds[HH];
    __shared__ float g_lds[2 * RPB];   // [half][row]
    __shared__ float bias_lds[RPB];
    __shared__ float wih_lds[RPB];
    __shared__ float x_lds[2 * TT];
    __shared__ float h_hist[2][UPB];   // own-slice h history (store decouple)

    for (int i = tid; i < TT; i += 512) {
        x_lds[i] = seq[b * TT + i];
        x_lds[TT + i] = target[b * TT + i];
    }

    float4 w[32];
    auto loadw = [&](const float* Whh, const float* Wih,
                     const float* bih, const float* bhh) {
        const float4* wr = (const float4*)(Whh + row_global * HH + half * 128);
#pragma unroll
        for (int i = 0; i < 32; ++i) w[i] = wr[i];
        if (half == 0) {
            bias_lds[row] = bih[row_global] + bhh[row_global];
            wih_lds[row] = Wih[row_global];
        }
    };
    loadw(Whh_e, Wih_e, bih_e, bhh_e);

    if (tid < 64) ((float4*)h_lds)[tid] = make_float4(0.f, 0.f, 0.f, 0.f);
    __syncthreads();

    float c = 0.f, c_saved = 0.f, h_saved = 0.f;

    for (int t = 0; t < 2 * TT; ++t) {
        const int phase = t >> 7;  // 0 = encoder, 1 = decoder
        const int tt = t & 127;

        // ---- phase 1: half-row dot product, single-address broadcast ----
        const float4* h4 = (const float4*)(h_lds + (half << 7));
        float4 a4 = make_float4(0.f, 0.f, 0.f, 0.f);
#pragma unroll
        for (int i = 0; i < 32; ++i) {
            float4 hv = h4[i];  // one address for all 64 lanes -> broadcast
            a4.x = fmaf(w[i].x, hv.x, a4.x);
            a4.y = fmaf(w[i].y, hv.y, a4.y);
            a4.z = fmaf(w[i].z, hv.z, a4.z);
            a4.w = fmaf(w[i].w, hv.w, a4.w);
        }
        g_lds[(half << 8) + row] = (a4.x + a4.y) + (a4.z + a4.w);
        __syncthreads();  // (A) partials visible; h_lds free to overwrite

        // ---- phase 2 (wave 0): combine + nonlin + publish (mbox only) ----
        if (tid < 64) {
            const float x = x_lds[t];
            float gi = g_lds[tid] + g_lds[256 + tid] + bias_lds[tid] +
                       x * wih_lds[tid];
            float gf = g_lds[64 + tid] + g_lds[320 + tid] + bias_lds[64 + tid] +
                       x * wih_lds[64 + tid];
            float gg = g_lds[128 + tid] + g_lds[384 + tid] + bias_lds[128 + tid] +
                       x * wih_lds[128 + tid];
            float go = g_lds[192 + tid] + g_lds[448 + tid] + bias_lds[192 + tid] +
                       x * wih_lds[192 + tid];
            float si = sigmoid_f(gi);
            float sf = sigmoid_f(gf);
            float tg = tanh_f(gg);
            float so = sigmoid_f(go);
            c = sf * c + si * tg;
            float h = so * tanh_f(c);
            const int ug = g * UPB + tid;
            // publish FIRST: the only VMEM op wave 0 must drain pre-barrier
            unsigned long long pkt =
                ((unsigned long long)(unsigned)(t + 1) << 32) | __float_as_uint(h);
            __hip_atomic_store(&mbox[(t & 1) * BB * HH + b * HH + ug], pkt,
                               __ATOMIC_RELAXED, AGENT);
            if (phase == 0 && tt == last) {
                c_saved = c;
                h_saved = h;
                unsigned long long spkt =
                    (1ull << 32) | (unsigned long long)__float_as_uint(h);
                __hip_atomic_store(&hsave[b * HH + ug], spkt, __ATOMIC_RELAXED, AGENT);
            }
            h_lds[ug] = (t == TT - 1) ? h_saved : h;
            h_hist[t & 1][tid] = h;  // store decoupling: wave 4 writes global
        }

        // ---- phase 2b (wave 4): write PREVIOUS step's h to global ----
        if (wave == 4 && t > 0) {
            const int pt = t - 1;
            float hv = h_hist[pt & 1][lane];
            ((pt >> 7) ? d_out : e_out)[(b * TT + (pt & 127)) * HH + g * UPB + lane] = hv;
        }

        // ---- phase 3 (waves 1..3): ring poll, back-to-back prefill ----
        if (wave >= 1 && wave <= 3) {
            const int p = (g + wave) & 3;  // partner slice 1..3 away
            const int pu = p * UPB + lane;
            unsigned long long* src;
            unsigned want;
            if (t == TT - 1) {
                src = &hsave[b * HH + pu];
                want = 1u;
            } else {
                src = &mbox[(t & 1) * BB * HH + b * HH + pu];
                want = (unsigned)(t + 1);
            }
            unsigned long long pv;
            {
                // 4 loads in flight; steady-state resample cadence ~= loop time
                unsigned long long r0 = AL(src);
                unsigned long long r1 = AL(src);
                unsigned long long r2 = AL(src);
                unsigned long long r3 = AL(src);
                for (;;) {
                    if ((unsigned)(r0 >> 32) == want) { pv = r0; break; }
                    r0 = AL(src);
                    if ((unsigned)(r1 >> 32) == want) { pv = r1; break; }
                    r1 = AL(src);
                    if ((unsigned)(r2 >> 32) == want) { pv = r2; break; }
                    r2 = AL(src);
                    if ((unsigned)(r3 >> 32) == want) { pv = r3; break; }
                    r3 = AL(src);
                }
            }
            h_lds[pu] = __uint_as_float((unsigned)pv);
        }
        __syncthreads();  // (B) h_lds complete for next step

        if (t == TT - 1) {  // encoder -> decoder transition
            loadw(Whh_d, Wih_d, bih_d, bhh_d);
            c = c_saved;
        }
    }

    // flush the final step's h (t = 2*TT-1)
    if (wave == 4) {
        float hv = h_hist[1][lane];  // (2*TT-1) & 1 == 1
        d_out[(b * TT + (TT - 1)) * HH + g * UPB + lane] = hv;
    }
}

// ---------------------------------------------------------------------------
// Projections: e2 = e @ We^T + be ; d2 = d @ Wd^T + bd.
// ---------------------------------------------------------------------------
__global__ __launch_bounds__(256) void proj_kernel(
    const float* __restrict__ e_in, const float* __restrict__ d_in,
    const float* __restrict__ WeT, const float* __restrict__ WdT,
    const float* __restrict__ be, const float* __restrict__ bd,
    float* __restrict__ e2, float* __restrict__ d2) {
    __shared__ float tile[16][HH];
    const int blk = blockIdx.x;
    const bool isd = blk >= 256;
    const float* in = isd ? d_in : e_in;
    const float* WT = isd ? WdT : WeT;
    const float* bias = isd ? bd : be;
    float* out = isd ? d2 : e2;
    const int r0 = (isd ? blk - 256 : blk) * 16;
    const int tid = threadIdx.x;

    {
        const float4* src = (const float4*)(in + r0 * HH);
        float4* dst = (float4*)(&tile[0][0]);
        for (int idx = tid; idx < 16 * 64; idx += 256) dst[idx] = src[idx];
    }
    __syncthreads();

    float acc[16];
#pragma unroll
    for (int r = 0; r < 16; ++r) acc[r] = 0.f;
    const int cidx = tid;
    for (int k = 0; k < HH; k += 4) {
        float w0 = WT[(k + 0) * HH + cidx];
        float w1 = WT[(k + 1) * HH + cidx];
        float w2 = WT[(k + 2) * HH + cidx];
        float w3 = WT[(k + 3) * HH + cidx];
#pragma unroll
        for (int r = 0; r < 16; ++r) {
            float4 iv = *(const float4*)&tile[r][k];  // LDS broadcast
            acc[r] = fmaf(iv.x, w0, acc[r]);
            acc[r] = fmaf(iv.y, w1, acc[r]);
            acc[r] = fmaf(iv.z, w2, acc[r]);
            acc[r] = fmaf(iv.w, w3, acc[r]);
        }
    }
    const float bb = bias[cidx];
#pragma unroll
    for (int r = 0; r < 16; ++r) out[(r0 + r) * HH + cidx] = acc[r] + bb;
}

// ---------------------------------------------------------------------------
// Attention + mask + softmax, 4x i-register-blocked.
// ---------------------------------------------------------------------------
#define EPAD 260  // float4-aligned LDS row stride
#define PPAD 132
__global__ __launch_bounds__(256) void attn_kernel(
    const float* __restrict__ e2, const float* __restrict__ d2,
    const float* __restrict__ vv, const float* __restrict__ seq,
    float* __restrict__ out) {
    __shared__ float e2c[32][EPAD];
    __shared__ float d2t[32][EPAD];
    __shared__ float p_lds[32][PPAD];
    __shared__ float v_lds[HH];

    const int blk = blockIdx.x;
    const int b = blk >> 2;
    const int i0 = (blk & 3) * 32;
    const int tid = threadIdx.x;
    const int jl = tid & 31, ig = tid >> 5;  // ig in 0..7 -> 4 i's each

    if (tid < 64) *(float4*)&v_lds[tid * 4] = ((const float4*)vv)[tid];
    for (int idx = tid; idx < 32 * 64; idx += 256) {
        int r = idx >> 6, q = idx & 63;
        *(float4*)&d2t[r][q * 4] = ((const float4*)(d2 + (b * TT + i0 + r) * HH))[q];
    }

    for (int jc = 0; jc < TT; jc += 32) {
        __syncthreads();
        for (int idx = tid; idx < 32 * 64; idx += 256) {
            int r = idx >> 6, q = idx & 63;
            *(float4*)&e2c[r][q * 4] = ((const float4*)(e2 + (b * TT + jc + r) * HH))[q];
        }
        __syncthreads();

        float a0 = 0.f, a1 = 0.f, a2 = 0.f, a3 = 0.f;
        for (int h = 0; h < HH; h += 4) {
            float4 ev = *(const float4*)&e2c[jl][h];
            float4 vx = *(const float4*)&v_lds[h];
            float4 d0 = *(const float4*)&d2t[ig * 4 + 0][h];
            float4 d1 = *(const float4*)&d2t[ig * 4 + 1][h];
            float4 d2v = *(const float4*)&d2t[ig * 4 + 2][h];
            float4 d3 = *(const float4*)&d2t[ig * 4 + 3][h];
            a0 = fmaf(tanh_f(ev.x + d0.x), vx.x, a0);
            a0 = fmaf(tanh_f(ev.y + d0.y), vx.y, a0);
            a0 = fmaf(tanh_f(ev.z + d0.z), vx.z, a0);
            a0 = fmaf(tanh_f(ev.w + d0.w), vx.w, a0);
            a1 = fmaf(tanh_f(ev.x + d1.x), vx.x, a1);
            a1 = fmaf(tanh_f(ev.y + d1.y), vx.y, a1);
            a1 = fmaf(tanh_f(ev.z + d1.z), vx.z, a1);
            a1 = fmaf(tanh_f(ev.w + d1.w), vx.w, a1);
            a2 = fmaf(tanh_f(ev.x + d2v.x), vx.x, a2);
            a2 = fmaf(tanh_f(ev.y + d2v.y), vx.y, a2);
            a2 = fmaf(tanh_f(ev.z + d2v.z), vx.z, a2);
            a2 = fmaf(tanh_f(ev.w + d2v.w), vx.w, a2);
            a3 = fmaf(tanh_f(ev.x + d3.x), vx.x, a3);
            a3 = fmaf(tanh_f(ev.y + d3.y), vx.y, a3);
            a3 = fmaf(tanh_f(ev.z + d3.z), vx.z, a3);
            a3 = fmaf(tanh_f(ev.w + d3.w), vx.w, a3);
        }
        const int j = jc + jl;
        float sv = (j == 0) ? 0.1f : seq[b * TT + j];
        float msk = (sv == 0.f) ? -1000.f : 0.f;
        p_lds[ig * 4 + 0][j] = a0 + msk;
        p_lds[ig * 4 + 1][j] = a1 + msk;
        p_lds[ig * 4 + 2][j] = a2 + msk;
        p_lds[ig * 4 + 3][j] = a3 + msk;
    }
    __syncthreads();

    // softmax: 32 rows x 8 lanes, 16 j per lane
    const int r = tid >> 3, l8 = tid & 7;
    float xr[16];
    float m = -1e30f;
#pragma unroll
    for (int k = 0; k < 16; ++k) {
        xr[k] = p_lds[r][l8 + 8 * k];
        m = fmaxf(m, xr[k]);
    }
#pragma unroll
    for (int o = 4; o >= 1; o >>= 1) m = fmaxf(m, __shfl_xor(m, o));
    float s = 0.f;
#pragma unroll
    for (int k = 0; k < 16; ++k) {
        xr[k] = __expf(xr[k] - m);
        s += xr[k];
    }
#pragma unroll
    for (int o = 4; o >= 1; o >>= 1) s += __shfl_xor(s, o);
    float inv = rcp_f(s);
    float* orow = out + (b * TT + i0 + r) * TT;
#pragma unroll
    for (int k = 0; k < 16; ++k) orow[l8 + 8 * k] = xr[k] * inv;
}

// ---------------------------------------------------------------------------
extern "C" void kernel_launch(void* const* d_in, const int* in_sizes, int n_in,
                              void* d_out, int out_size, void* d_ws, size_t ws_size,
                              hipStream_t stream) {
    const float* seq = (const float*)d_in[0];
    const int* seq_m = (const int*)d_in[1];
    const float* target = (const float*)d_in[2];
    const float* Wih_e = (const float*)d_in[3];
    const float* Whh_e = (const float*)d_in[4];
    const float* bih_e = (const float*)d_in[5];
    const float* bhh_e = (const float*)d_in[6];
    const float* Wih_d = (const float*)d_in[7];
    const float* Whh_d = (const float*)d_in[8];
    const float* bih_d = (const float*)d_in[9];
    const float* bhh_d = (const float*)d_in[10];
    const float* We = (const float*)d_in[11];
    const float* be = (const float*)d_in[12];
    const float* Wd = (const float*)d_in[13];
    const float* bd = (const float*)d_in[14];
    const float* vv = (const float*)d_in[15];

    float* ws = (float*)d_ws;
    const size_t SZ_ED = (size_t)BB * TT * HH;  // 1,048,576 floats
    float* e_buf = ws;
    float* d_buf = e_buf + SZ_ED;
    float* e2 = d_buf + SZ_ED;
    float* d2 = e2 + SZ_ED;
    float* WeT = d2 + SZ_ED;
    float* WdT = WeT + HH * HH;
    unsigned long long* mbox = (unsigned long long*)(WdT + HH * HH);  // [2][B][H]
    unsigned long long* hsave = mbox + 2 * BB * HH;                   // [B][H]

    const size_t needed = (4 * SZ_ED + 2 * HH * HH) * sizeof(float) +
                          3 * BB * HH * sizeof(unsigned long long);
    if (ws_size < needed) return;

    hipMemsetAsync(mbox, 0, 3 * BB * HH * sizeof(unsigned long long), stream);
    prep_transpose<<<32, 256, 0, stream>>>(We, Wd, WeT, WdT);
    lstm_kernel<<<BB * G4, 512, 0, stream>>>(seq, seq_m, target, Wih_e, Whh_e, bih_e,
                                             bhh_e, Wih_d, Whh_d, bih_d, bhh_d, e_buf,
                                             d_buf, mbox, hsave);
    proj_kernel<<<512, 256, 0, stream>>>(e_buf, d_buf, WeT, WdT, be, bd, e2, d2);
    attn_kernel<<<BB * 4, 256, 0, stream>>>(e2, d2, vv, seq, (float*)d_out);
}

// Round 10
// 687.510 us; speedup vs baseline: 1.0202x; 1.0202x over previous
//
#include <hip/hip_runtime.h>
#include <hip/hip_bf16.h>

// Problem constants
#define BB 32    // batch
#define TT 128   // T_E == T_D
#define HH 256   // hidden
#define G4 4     // blocks per batch for LSTM
#define UPB 64   // units per LSTM block (256/4)
#define RPB 256  // gate rows per LSTM block (4 gates * 64 units)

#define AGENT __HIP_MEMORY_SCOPE_AGENT
#define AL(p) __hip_atomic_load((p), __ATOMIC_RELAXED, AGENT)

__device__ __forceinline__ float rcp_f(float x) { return __builtin_amdgcn_rcpf(x); }
__device__ __forceinline__ float sigmoid_f(float x) {
    return rcp_f(1.f + __expf(-x));  // v_rcp: ~1e-7 rel err vs 7e-3 threshold
}
__device__ __forceinline__ float tanh_f(float x) {
    float e = __expf(2.f * x);
    return 1.f - 2.f * rcp_f(e + 1.f);
}

// ---------------------------------------------------------------------------
// Prep: transpose We, Wd (256x256), tiled+coalesced.
// ---------------------------------------------------------------------------
__global__ __launch_bounds__(256) void prep_transpose(
    const float* __restrict__ We, const float* __restrict__ Wd,
    float* __restrict__ WeT, float* __restrict__ WdT) {
    __shared__ float t[64][65];
    const int m = blockIdx.x >> 4;
    const int tile = blockIdx.x & 15;
    const float* S = m ? Wd : We;
    float* D = m ? WdT : WeT;
    const int r0 = (tile >> 2) * 64, c0 = (tile & 3) * 64;
    const int lr = threadIdx.x >> 4;
    const int lc = threadIdx.x & 15;
    for (int rr = lr; rr < 64; rr += 16)
        *(float4*)&t[rr][lc * 4] = *(const float4*)&S[(r0 + rr) * HH + c0 + lc * 4];
    __syncthreads();
    for (int rr = lr; rr < 64; rr += 16) {
        float4 v;
        v.x = t[lc * 4 + 0][rr];
        v.y = t[lc * 4 + 1][rr];
        v.z = t[lc * 4 + 2][rr];
        v.w = t[lc * 4 + 3][rr];
        *(float4*)&D[(c0 + rr) * HH + r0 + lc * 4] = v;
    }
}

// ---------------------------------------------------------------------------
// LSTM — R7 lean-phase-2 structure (best measured: 484us) + vetted tweaks.
// grid = 128 (blk = g*32 + b); block = 512; Whh slice in registers.
// Thread (row=tid>>1, half=tid&1): 128-wide k-slice dot; shfl_xor(1) combines
// halves; bias + x*Wih folded in PER-ROW (parallel, off the serial path).
// Phase 2 (wave 0, SERIAL path) kept minimal: 4 LDS reads + activations +
// publish. 2-way LDS conflicts in phase 1 are free (m136) - left as is.
// Poll: 4-deep ring, back-to-back prefill, no sleeps. Tag-in-data mailbox
// (u64 = tag<<32|bits), relaxed agent-scope only; ping-pong slot; monotonic
// tags make slot reuse safe (R3 causal-chain argument).
// ---------------------------------------------------------------------------
__global__ __launch_bounds__(512, 2) void lstm_kernel(
    const float* __restrict__ seq,     // [B][128]
    const int* __restrict__ seq_m,     // [B]
    const float* __restrict__ target,  // [B][128]
    const float* __restrict__ Wih_e,   // [1024]
    const float* __restrict__ Whh_e,   // [1024][256]
    const float* __restrict__ bih_e, const float* __restrict__ bhh_e,
    const float* __restrict__ Wih_d, const float* __restrict__ Whh_d,
    const float* __restrict__ bih_d, const float* __restrict__ bhh_d,
    float* __restrict__ e_out,  // [B][128][256]
    float* __restrict__ d_out,  // [B][128][256]
    unsigned long long* __restrict__ mbox,   // [2][B][256] tagged h packets
    unsigned long long* __restrict__ hsave)  // [B][256] tag-1 enc state @ last
{
    const int blk = blockIdx.x;
    const int b = blk & 31;   // batch
    const int g = blk >> 5;   // group slice 0..3
    const int tid = threadIdx.x;
    const int row_local = tid >> 1;  // 0..255
    const int half = tid & 1;        // k-half
    const int gate = row_local >> 6; // 0..3 (i,f,g,o)
    const int u_local = row_local & 63;
    const int row_global = gate * HH + g * UPB + u_local;
    const int last = seq_m[b] - 1;

    __shared__ float h_lds[HH];
    __shared__ float g_lds[RPB];
    __shared__ float x_lds[2 * TT];

    for (int i = tid; i < TT; i += 512) {
        x_lds[i] = seq[b * TT + i];
        x_lds[TT + i] = target[b * TT + i];
    }

    float4 w[32];
    float bias_r, wih_r;
    auto loadw = [&](const float* Whh, const float* Wih,
                     const float* bih, const float* bhh) {
        const float4* wr = (const float4*)(Whh + row_global * HH + half * 128);
#pragma unroll
        for (int i = 0; i < 32; ++i) w[i] = wr[i];
        bias_r = bih[row_global] + bhh[row_global];
        wih_r = Wih[row_global];
    };
    loadw(Whh_e, Wih_e, bih_e, bhh_e);

    if (tid < 64) ((float4*)h_lds)[tid] = make_float4(0.f, 0.f, 0.f, 0.f);
    __syncthreads();

    float c = 0.f, c_saved = 0.f, h_saved = 0.f;

    for (int t = 0; t < 2 * TT; ++t) {
        const int phase = t >> 7;  // 0 = encoder, 1 = decoder
        const int tt = t & 127;
        const float x = x_lds[t];

        // ---- phase 1: gate-row dot product over own 128-wide k-slice ----
        const float4* h4 = ((const float4*)h_lds) + half * 32;
        float4 a4 = make_float4(0.f, 0.f, 0.f, 0.f);
#pragma unroll
        for (int i = 0; i < 32; ++i) {
            float4 hv = h4[i];
            a4.x = fmaf(w[i].x, hv.x, a4.x);
            a4.y = fmaf(w[i].y, hv.y, a4.y);
            a4.z = fmaf(w[i].z, hv.z, a4.z);
            a4.w = fmaf(w[i].w, hv.w, a4.w);
        }
        float acc = (a4.x + a4.y) + (a4.z + a4.w);
        acc += __shfl_xor(acc, 1);  // combine the two k-halves
        float gv = acc + bias_r + x * wih_r;  // bias/Wih folded OFF serial path
        if (half == 0) g_lds[row_local] = gv;
        __syncthreads();  // (A) gates visible; h_lds free to overwrite

        // ---- phase 2 (wave 0): minimal serial segment ----
        if (tid < 64) {
            float gi = g_lds[tid];
            float gf = g_lds[64 + tid];
            float gg = g_lds[128 + tid];
            float go = g_lds[192 + tid];
            float si = sigmoid_f(gi);
            float sf = sigmoid_f(gf);
            float tg = tanh_f(gg);
            float so = sigmoid_f(go);
            c = sf * c + si * tg;
            float h = so * tanh_f(c);
            const int ug = g * UPB + tid;
            // publish FIRST: this store is the step's critical path
            unsigned long long pkt =
                ((unsigned long long)(unsigned)(t + 1) << 32) | __float_as_uint(h);
            __hip_atomic_store(&mbox[(t & 1) * BB * HH + b * HH + ug], pkt,
                               __ATOMIC_RELAXED, AGENT);
            if (phase == 0 && tt == last) {
                c_saved = c;
                h_saved = h;
                unsigned long long spkt =
                    (1ull << 32) | (unsigned long long)__float_as_uint(h);
                __hip_atomic_store(&hsave[b * HH + ug], spkt, __ATOMIC_RELAXED, AGENT);
            }
            h_lds[ug] = (t == TT - 1) ? h_saved : h;
            (phase ? d_out : e_out)[(b * TT + tt) * HH + ug] = h;
        }

        // ---- phase 3 (waves 1..3): ring poll, back-to-back prefill ----
        if (tid >= 64 && tid < 256) {
            const int p = (g + (tid >> 6)) & 3;  // partner slice 1..3 away
            const int lane = tid & 63;
            const int pu = p * UPB + lane;
            unsigned long long* src;
            unsigned want;
            if (t == TT - 1) {
                src = &hsave[b * HH + pu];
                want = 1u;
            } else {
                src = &mbox[(t & 1) * BB * HH + b * HH + pu];
                want = (unsigned)(t + 1);
            }
            unsigned long long pv;
            {
                // 4 loads in flight; steady-state resample cadence = loop time
                unsigned long long r0 = AL(src);
                unsigned long long r1 = AL(src);
                unsigned long long r2 = AL(src);
                unsigned long long r3 = AL(src);
                for (;;) {
                    if ((unsigned)(r0 >> 32) == want) { pv = r0; break; }
                    r0 = AL(src);
                    if ((unsigned)(r1 >> 32) == want) { pv = r1; break; }
                    r1 = AL(src);
                    if ((unsigned)(r2 >> 32) == want) { pv = r2; break; }
                    r2 = AL(src);
                    if ((unsigned)(r3 >> 32) == want) { pv = r3; break; }
                    r3 = AL(src);
                }
            }
            h_lds[pu] = __uint_as_float((unsigned)pv);
        }
        __syncthreads();  // (B) h_lds complete for next step

        if (t == TT - 1) {  // encoder -> decoder transition
            loadw(Whh_d, Wih_d, bih_d, bhh_d);
            c = c_saved;
        }
    }
}

// ---------------------------------------------------------------------------
// Projections: e2 = e @ We^T + be ; d2 = d @ Wd^T + bd.
// ---------------------------------------------------------------------------
__global__ __launch_bounds__(256) void proj_kernel(
    const float* __restrict__ e_in, const float* __restrict__ d_in,
    const float* __restrict__ WeT, const float* __restrict__ WdT,
    const float* __restrict__ be, const float* __restrict__ bd,
    float* __restrict__ e2, float* __restrict__ d2) {
    __shared__ float tile[16][HH];
    const int blk = blockIdx.x;
    const bool isd = blk >= 256;
    const float* in = isd ? d_in : e_in;
    const float* WT = isd ? WdT : WeT;
    const float* bias = isd ? bd : be;
    float* out = isd ? d2 : e2;
    const int r0 = (isd ? blk - 256 : blk) * 16;
    const int tid = threadIdx.x;

    {
        const float4* src = (const float4*)(in + r0 * HH);
        float4* dst = (float4*)(&tile[0][0]);
        for (int idx = tid; idx < 16 * 64; idx += 256) dst[idx] = src[idx];
    }
    __syncthreads();

    float acc[16];
#pragma unroll
    for (int r = 0; r < 16; ++r) acc[r] = 0.f;
    const int cidx = tid;
    for (int k = 0; k < HH; k += 4) {
        float w0 = WT[(k + 0) * HH + cidx];
        float w1 = WT[(k + 1) * HH + cidx];
        float w2 = WT[(k + 2) * HH + cidx];
        float w3 = WT[(k + 3) * HH + cidx];
#pragma unroll
        for (int r = 0; r < 16; ++r) {
            float4 iv = *(const float4*)&tile[r][k];  // LDS broadcast
            acc[r] = fmaf(iv.x, w0, acc[r]);
            acc[r] = fmaf(iv.y, w1, acc[r]);
            acc[r] = fmaf(iv.z, w2, acc[r]);
            acc[r] = fmaf(iv.w, w3, acc[r]);
        }
    }
    const float bb = bias[cidx];
#pragma unroll
    for (int r = 0; r < 16; ++r) out[(r0 + r) * HH + cidx] = acc[r] + bb;
}

// ---------------------------------------------------------------------------
// Attention + mask + softmax, 2x i-register-blocked, 256 blocks (all CUs).
// grid = 32 b x 8 i-tiles (16 i each); block = 256 threads.
// ---------------------------------------------------------------------------
#define EPAD 260  // float4-aligned LDS row stride
#define PPAD 132
__global__ __launch_bounds__(256) void attn_kernel(
    const float* __restrict__ e2, const float* __restrict__ d2,
    const float* __restrict__ vv, const float* __restrict__ seq,
    float* __restrict__ out) {
    __shared__ float e2c[32][EPAD];
    __shared__ float d2t[16][EPAD];
    __shared__ float p_lds[16][PPAD];
    __shared__ float v_lds[HH];

    const int blk = blockIdx.x;
    const int b = blk >> 3;
    const int i0 = (blk & 7) * 16;
    const int tid = threadIdx.x;
    const int jl = tid & 31, ig = tid >> 5;  // ig 0..7 -> 2 i-rows each

    if (tid < 64) *(float4*)&v_lds[tid * 4] = ((const float4*)vv)[tid];
    for (int idx = tid; idx < 16 * 64; idx += 256) {
        int r = idx >> 6, q = idx & 63;
        *(float4*)&d2t[r][q * 4] = ((const float4*)(d2 + (b * TT + i0 + r) * HH))[q];
    }

    for (int jc = 0; jc < TT; jc += 32) {
        __syncthreads();
        for (int idx = tid; idx < 32 * 64; idx += 256) {
            int r = idx >> 6, q = idx & 63;
            *(float4*)&e2c[r][q * 4] = ((const float4*)(e2 + (b * TT + jc + r) * HH))[q];
        }
        __syncthreads();

        float a0 = 0.f, a1 = 0.f;
        for (int h = 0; h < HH; h += 4) {
            float4 ev = *(const float4*)&e2c[jl][h];
            float4 vx = *(const float4*)&v_lds[h];
            float4 d0 = *(const float4*)&d2t[ig * 2 + 0][h];
            float4 d1 = *(const float4*)&d2t[ig * 2 + 1][h];
            a0 = fmaf(tanh_f(ev.x + d0.x), vx.x, a0);
            a0 = fmaf(tanh_f(ev.y + d0.y), vx.y, a0);
            a0 = fmaf(tanh_f(ev.z + d0.z), vx.z, a0);
            a0 = fmaf(tanh_f(ev.w + d0.w), vx.w, a0);
            a1 = fmaf(tanh_f(ev.x + d1.x), vx.x, a1);
            a1 = fmaf(tanh_f(ev.y + d1.y), vx.y, a1);
            a1 = fmaf(tanh_f(ev.z + d1.z), vx.z, a1);
            a1 = fmaf(tanh_f(ev.w + d1.w), vx.w, a1);
        }
        const int j = jc + jl;
        float sv = (j == 0) ? 0.1f : seq[b * TT + j];
        float msk = (sv == 0.f) ? -1000.f : 0.f;
        p_lds[ig * 2 + 0][j] = a0 + msk;
        p_lds[ig * 2 + 1][j] = a1 + msk;
    }
    __syncthreads();

    // softmax: 16 rows x 16 lanes, 8 j per lane
    const int r = tid >> 4, l16 = tid & 15;
    float xr[8];
    float m = -1e30f;
#pragma unroll
    for (int k = 0; k < 8; ++k) {
        xr[k] = p_lds[r][l16 + 16 * k];
        m = fmaxf(m, xr[k]);
    }
#pragma unroll
    for (int o = 8; o >= 1; o >>= 1) m = fmaxf(m, __shfl_xor(m, o));
    float s = 0.f;
#pragma unroll
    for (int k = 0; k < 8; ++k) {
        xr[k] = __expf(xr[k] - m);
        s += xr[k];
    }
#pragma unroll
    for (int o = 8; o >= 1; o >>= 1) s += __shfl_xor(s, o);
    float inv = rcp_f(s);
    float* orow = out + (b * TT + i0 + r) * TT;
#pragma unroll
    for (int k = 0; k < 8; ++k) orow[l16 + 16 * k] = xr[k] * inv;
}

// ---------------------------------------------------------------------------
extern "C" void kernel_launch(void* const* d_in, const int* in_sizes, int n_in,
                              void* d_out, int out_size, void* d_ws, size_t ws_size,
                              hipStream_t stream) {
    const float* seq = (const float*)d_in[0];
    const int* seq_m = (const int*)d_in[1];
    const float* target = (const float*)d_in[2];
    const float* Wih_e = (const float*)d_in[3];
    const float* Whh_e = (const float*)d_in[4];
    const float* bih_e = (const float*)d_in[5];
    const float* bhh_e = (const float*)d_in[6];
    const float* Wih_d = (const float*)d_in[7];
    const float* Whh_d = (const float*)d_in[8];
    const float* bih_d = (const float*)d_in[9];
    const float* bhh_d = (const float*)d_in[10];
    const float* We = (const float*)d_in[11];
    const float* be = (const float*)d_in[12];
    const float* Wd = (const float*)d_in[13];
    const float* bd = (const float*)d_in[14];
    const float* vv = (const float*)d_in[15];

    float* ws = (float*)d_ws;
    const size_t SZ_ED = (size_t)BB * TT * HH;  // 1,048,576 floats
    float* e_buf = ws;
    float* d_buf = e_buf + SZ_ED;
    float* e2 = d_buf + SZ_ED;
    float* d2 = e2 + SZ_ED;
    float* WeT = d2 + SZ_ED;
    float* WdT = WeT + HH * HH;
    unsigned long long* mbox = (unsigned long long*)(WdT + HH * HH);  // [2][B][H]
    unsigned long long* hsave = mbox + 2 * BB * HH;                   // [B][H]

    const size_t needed = (4 * SZ_ED + 2 * HH * HH) * sizeof(float) +
                          3 * BB * HH * sizeof(unsigned long long);
    if (ws_size < needed) return;

    hipMemsetAsync(mbox, 0, 3 * BB * HH * sizeof(unsigned long long), stream);
    prep_transpose<<<32, 256, 0, stream>>>(We, Wd, WeT, WdT);
    lstm_kernel<<<BB * G4, 512, 0, stream>>>(seq, seq_m, target, Wih_e, Whh_e, bih_e,
                                             bhh_e, Wih_d, Whh_d, bih_d, bhh_d, e_buf,
                                             d_buf, mbox, hsave);
    proj_kernel<<<512, 256, 0, stream>>>(e_buf, d_buf, WeT, WdT, be, bd, e2, d2);
    attn_kernel<<<BB * 8, 256, 0, stream>>>(e2, d2, vv, seq, (float*)d_out);
}